// Round 1
// baseline (894.129 us; speedup 1.0000x reference)
//
#include <hip/hip_runtime.h>
#include <math.h>

// ConvCapsuleLayer fused kernel (v1, fp32 correctness-first)
// x: [16,32,32,8,32] f32; W: [5,5,32,256] f32; b: [1,1,16,16] f32
// out: activation [16,32,32,16,16] f32
//
// One block = 4 pixels (b, h, w0..w0+3), 256 threads.
// Phase 1: load input patch [ci=8][dh=5][dw=8][ai=32] to LDS (40KB)
// Phase 2: conv -> votes (regs), thread: ci=tid>>5, cols c0=(tid&31)*8, 4 pixels
// Phase 3: votes -> LDS (aliasing patch buffer), 3 routing iterations, write out.

#define PIX 4

__global__ __launch_bounds__(256, 2)
void caps_fused(const float* __restrict__ x, const float* __restrict__ Wg,
                const float* __restrict__ bptr, float* __restrict__ out) {
    __shared__ float smem[10240];        // 40KB: input patch, later votes[4][2048]
    __shared__ float route_l[4 * 128];
    __shared__ float act_l[4 * 256];
    __shared__ float logit_l[4 * 128];

    const int tid = threadIdx.x;
    const int bid = blockIdx.x;
    const int w0 = (bid & 7) * PIX;
    const int h  = (bid >> 3) & 31;
    const int b  = bid >> 8;

    // ---- Phase 1: input patch ----
    // smem[((ci*5+dh)*8+dw)*32 + ai] = x[b][h+dh-2][w0+dw-2][ci][ai] (0 if OOB)
    {
        const int ci = tid >> 5, ai = tid & 31;
        const int hbase = h - 2, wbase = w0 - 2;
        for (int loc = 0; loc < 40; ++loc) {
            const int dh = loc >> 3, dw = loc & 7;
            const int gh = hbase + dh, gw = wbase + dw;
            float v = 0.f;
            if ((unsigned)gh < 32u && (unsigned)gw < 32u)
                v = x[(((b * 32 + gh) * 32 + gw) * 256) + tid];
            smem[((ci * 5 + dh) * 8 + dw) * 32 + ai] = v;
        }
    }
    __syncthreads();

    // ---- Phase 2: conv ----
    const int ci = tid >> 5;
    const int c0 = (tid & 31) * 8;
    float acc[PIX][8];
#pragma unroll
    for (int p = 0; p < PIX; ++p)
#pragma unroll
        for (int j = 0; j < 8; ++j) acc[p][j] = 0.f;

    const float* ibase = &smem[ci * 5 * 8 * 32];
    for (int k5 = 0; k5 < 25; ++k5) {
        const int kh = k5 / 5, kw = k5 % 5;
        const float* ilp = ibase + (kh * 8 + kw) * 32;
        const float* wp = Wg + k5 * 8192 + c0;
#pragma unroll
        for (int ai4 = 0; ai4 < 32; ai4 += 4) {
            float4 av[PIX];
#pragma unroll
            for (int p = 0; p < PIX; ++p)
                av[p] = *(const float4*)(ilp + p * 32 + ai4);
#pragma unroll
            for (int u = 0; u < 4; ++u) {
                const int ai = ai4 + u;
                const float4 wlo = *(const float4*)(wp + ai * 256);
                const float4 whi = *(const float4*)(wp + ai * 256 + 4);
#pragma unroll
                for (int p = 0; p < PIX; ++p) {
                    const float a = (u == 0) ? av[p].x : (u == 1) ? av[p].y
                                  : (u == 2) ? av[p].z : av[p].w;
                    acc[p][0] += a * wlo.x; acc[p][1] += a * wlo.y;
                    acc[p][2] += a * wlo.z; acc[p][3] += a * wlo.w;
                    acc[p][4] += a * whi.x; acc[p][5] += a * whi.y;
                    acc[p][6] += a * whi.z; acc[p][7] += a * whi.w;
                }
            }
        }
    }
    __syncthreads();   // everyone done reading input patch

    // votes[p][ci*256 + c] aliases smem
#pragma unroll
    for (int p = 0; p < PIX; ++p) {
        float4 v0 = make_float4(acc[p][0], acc[p][1], acc[p][2], acc[p][3]);
        float4 v1 = make_float4(acc[p][4], acc[p][5], acc[p][6], acc[p][7]);
        *(float4*)&smem[p * 2048 + ci * 256 + c0]     = v0;
        *(float4*)&smem[p * 2048 + ci * 256 + c0 + 4] = v1;
    }
    for (int i = tid; i < 512; i += 256) logit_l[i] = 0.f;
    __syncthreads();

    // ---- Phase 3: routing (3 iterations) ----
    for (int it = 0; it < 3; ++it) {
        // route = softmax(logits) over co ; i = p*128 + ci*16 + co, co = lane&15
        for (int i = tid; i < 512; i += 256) {
            float lg = logit_l[i];
            float mx = lg;
#pragma unroll
            for (int m = 1; m < 16; m <<= 1) mx = fmaxf(mx, __shfl_xor(mx, m, 16));
            float e = __expf(lg - mx);
            float s = e;
#pragma unroll
            for (int m = 1; m < 16; m <<= 1) s += __shfl_xor(s, m, 16);
            route_l[i] = e / s;
        }
        __syncthreads();
        // preact + squash ; i = p*256 + co*16 + ao, ao = lane&15
        for (int i = tid; i < 1024; i += 256) {
            const int p = i >> 8, c = i & 255, co = c >> 4;
            float pr = bptr[c];
#pragma unroll
            for (int cc = 0; cc < 8; ++cc)
                pr += route_l[p * 128 + cc * 16 + co] * smem[p * 2048 + cc * 256 + c];
            float sq = pr * pr;
#pragma unroll
            for (int m = 1; m < 16; m <<= 1) sq += __shfl_xor(sq, m, 16);
            const float nrm = sqrtf(sq);
            act_l[i] = pr * nrm / (1.f + sq);   // == v/n * n^2/(1+n^2)
        }
        __syncthreads();
        if (it < 2) {
            // logits += sum_ao votes*act ; i = p*128 + ci*16 + co
            for (int i = tid; i < 512; i += 256) {
                const int p = i >> 7, r = i & 127;
                const int cc = r >> 4, co = r & 15;
                float d = 0.f;
#pragma unroll
                for (int ao = 0; ao < 16; ++ao)
                    d += smem[p * 2048 + cc * 256 + co * 16 + ao]
                       * act_l[p * 256 + co * 16 + ao];
                logit_l[i] += d;
            }
            __syncthreads();
        }
    }

    // ---- output: [b][h][w][co][ao] ----
    const int pixbase = ((b * 32 + h) * 32 + w0) * 256;
    for (int i = tid; i < 1024; i += 256) {
        const int p = i >> 8, c = i & 255;
        out[pixbase + p * 256 + c] = act_l[i];
    }
}

extern "C" void kernel_launch(void* const* d_in, const int* in_sizes, int n_in,
                              void* d_out, int out_size, void* d_ws, size_t ws_size,
                              hipStream_t stream) {
    const float* x  = (const float*)d_in[0];
    const float* W  = (const float*)d_in[1];
    const float* bb = (const float*)d_in[2];
    float* out = (float*)d_out;
    dim3 grid(16 * 32 * 8);   // B * H * (W/PIX)
    dim3 block(256);
    hipLaunchKernelGGL(caps_fused, grid, block, 0, stream, x, W, bb, out);
}

// Round 2
// 207.341 us; speedup vs baseline: 4.3124x; 4.3124x over previous
//
#include <hip/hip_runtime.h>
#include <math.h>

// ConvCapsuleLayer v2: MFMA bf16 conv + fused in-register routing.
// x: [16,32,32,8,32] f32; W: [5,5,32,256] f32; b: [1,1,16,16] f32
// out: [16,32,32,16,16] f32
//
// Block = 8 pixels (b,h,w0..w0+7) x 8 ci -> GEMM M=64 (r = p*8+ci), N=256, K=800.
// prep kernel: Wt[k5][c][ai] bf16 in d_ws (B-matrix, k=ai within k5 step).
// A staged in LDS bf16 [ci][dh=5][dw=12][ai=32], ci-stride padded.
// Routing fully fused; votes stay in MFMA accumulators.

typedef __attribute__((ext_vector_type(8))) short bf16x8;
typedef __attribute__((ext_vector_type(4))) float f32x4;

#define PADCI 1928   // halfwords per ci slice: 5*12*32=1920 (+8 pad)

static __device__ __forceinline__ unsigned short f2bf(float f) {
    union { float f; unsigned int u; } x; x.f = f;
    unsigned int u = x.u;
    u += 0x7FFFu + ((u >> 16) & 1u);   // RNE
    return (unsigned short)(u >> 16);
}

__global__ void prep_weights(const float* __restrict__ W, unsigned short* __restrict__ Wt) {
    int idx = blockIdx.x * 256 + threadIdx.x;          // [0, 25*256*32)
    if (idx >= 25 * 256 * 32) return;
    int k5 = idx >> 13;          // /8192
    int rem = idx & 8191;
    int c = rem >> 5, ai = rem & 31;
    Wt[idx] = f2bf(W[k5 * 8192 + ai * 256 + c]);
}

__global__ __launch_bounds__(256, 3)
void caps_mfma(const float* __restrict__ x, const unsigned short* __restrict__ Wt,
               const float* __restrict__ bptr, float* __restrict__ out) {
    __shared__ unsigned short patch[8 * PADCI];   // 30848 B
    __shared__ float route_l[8 * 16 * 8];         // [p][co][ci] 4KB
    __shared__ float logit_l[8 * 8 * 16];         // [p][ci][co] 4KB
    __shared__ float act_l[8 * 256];              // [p][co*16+ao] 8KB
    __shared__ float bias_l[256];

    const int tid = threadIdx.x;
    const int lane = tid & 63;
    const int wv = tid >> 6;
    const int bid = blockIdx.x;
    const int w0 = (bid & 3) * 8;
    const int h = (bid >> 2) & 31;
    const int b = bid >> 7;

    if (tid < 256) bias_l[tid] = bptr[tid];

    // ---- stage input patch (fp32 -> bf16 LDS) ----
    {
        const int ci = lane >> 3;
        const int a4 = (lane & 7) * 4;
        for (int r = 0; r < 15; ++r) {
            const int pos = r * 4 + wv;           // dh*12+dw, < 60
            const int dh = pos / 12, dw = pos - dh * 12;
            const int gh = h + dh - 2, gw = w0 + dw - 2;
            float4 v = make_float4(0.f, 0.f, 0.f, 0.f);
            if ((unsigned)gh < 32u && (unsigned)gw < 32u)
                v = *(const float4*)&x[(((b * 32 + gh) * 32 + gw) * 256) + lane * 4];
            unsigned short pk[4] = { f2bf(v.x), f2bf(v.y), f2bf(v.z), f2bf(v.w) };
            *(unsigned long long*)&patch[ci * PADCI + pos * 32 + a4] =
                *(unsigned long long*)pk;
        }
    }
    for (int i = tid; i < 1024; i += 256) logit_l[i] = 0.f;
    __syncthreads();

    // ---- conv: M=64, N=256, K=800 via 16x16x32 bf16 MFMA ----
    const int g = lane >> 4;      // k-group
    const int q = lane & 15;      // A-row / B-col / C-col within tile
    const unsigned short* aptr = patch + (lane & 7) * PADCI + (q >> 3) * 32 + g * 8;
    const unsigned short* bbase = Wt + (wv * 64 + q) * 32 + g * 8;

    f32x4 acc[4][4];
#pragma unroll
    for (int rb = 0; rb < 4; ++rb)
#pragma unroll
        for (int ct = 0; ct < 4; ++ct) acc[rb][ct] = (f32x4)0.f;

    bf16x8 Bc[4], Bn[4];
#pragma unroll
    for (int ct = 0; ct < 4; ++ct)
        Bc[ct] = *(const bf16x8*)(bbase + ct * 512);

    int k5 = 0;
#pragma unroll
    for (int kh = 0; kh < 5; ++kh) {
#pragma unroll
        for (int kw = 0; kw < 5; ++kw) {
            if (k5 < 24) {
                const unsigned short* bn = bbase + (k5 + 1) * 8192;
#pragma unroll
                for (int ct = 0; ct < 4; ++ct)
                    Bn[ct] = *(const bf16x8*)(bn + ct * 512);
            }
            const unsigned short* ap = aptr + (kh * 12 + kw) * 32;
            bf16x8 A[4];
#pragma unroll
            for (int rb = 0; rb < 4; ++rb)
                A[rb] = *(const bf16x8*)(ap + rb * 64);
#pragma unroll
            for (int rb = 0; rb < 4; ++rb)
#pragma unroll
                for (int ct = 0; ct < 4; ++ct)
                    acc[rb][ct] = __builtin_amdgcn_mfma_f32_16x16x32_bf16(
                        A[rb], Bc[ct], acc[rb][ct], 0, 0, 0);
#pragma unroll
            for (int ct = 0; ct < 4; ++ct) Bc[ct] = Bn[ct];
            ++k5;
        }
    }
    // lane holds: acc[rb][ct][j] = votes[p = rb*2+(g>>1)][ci = (g&1)*4+j]
    //                                   [co = wv*4+ct][ao = q]

    // ---- routing (3 iterations), votes in registers ----
    const int co_base = wv * 4;
    const int ao = q;
    float actreg[4][4];

    for (int it = 0; it < 3; ++it) {
        // softmax over co: logit_l [p][ci][co] -> route_l [p][co][ci]
        for (int i = tid; i < 1024; i += 256) {
            const int p = i >> 7, ci = (i >> 4) & 7, co = i & 15;
            float lg = logit_l[i];
            float mx = lg;
#pragma unroll
            for (int m = 1; m < 16; m <<= 1) mx = fmaxf(mx, __shfl_xor(mx, m));
            float e = __expf(lg - mx);
            float s = e;
#pragma unroll
            for (int m = 1; m < 16; m <<= 1) s += __shfl_xor(s, m);
            route_l[(p * 16 + co) * 8 + ci] = e / s;
        }
        __syncthreads();

        // preact + squash (per lane)
#pragma unroll
        for (int rb = 0; rb < 4; ++rb) {
#pragma unroll
            for (int ct = 0; ct < 4; ++ct) {
                const int p_ = rb * 2 + (g >> 1);
                const int cib = (g & 1) * 4;
                const int co = co_base + ct;
                const float4 r4 = *(const float4*)&route_l[(p_ * 16 + co) * 8 + cib];
                const f32x4 a = acc[rb][ct];
                float pr = r4.x * a.x + r4.y * a.y + r4.z * a.z + r4.w * a.w;
                pr += __shfl_xor(pr, 16);          // other ci-half (same p)
                pr += bias_l[co * 16 + ao];
                float sq = pr * pr;
#pragma unroll
                for (int m = 1; m < 16; m <<= 1) sq += __shfl_xor(sq, m);
                const float nrm = sqrtf(sq);
                actreg[rb][ct] = pr * nrm / (1.f + sq);
            }
        }

        if (it < 2) {
            // logits += sum_ao votes*act
#pragma unroll
            for (int rb = 0; rb < 4; ++rb) {
#pragma unroll
                for (int ct = 0; ct < 4; ++ct) {
                    const f32x4 a = acc[rb][ct];
                    const float av = actreg[rb][ct];
                    float d0 = a.x * av, d1 = a.y * av, d2 = a.z * av, d3 = a.w * av;
#pragma unroll
                    for (int m = 1; m < 16; m <<= 1) {
                        d0 += __shfl_xor(d0, m); d1 += __shfl_xor(d1, m);
                        d2 += __shfl_xor(d2, m); d3 += __shfl_xor(d3, m);
                    }
                    if (q == 0) {
                        const int p_ = rb * 2 + (g >> 1);
                        const int cib = (g & 1) * 4;
                        const int co = co_base + ct;
                        float* lg = &logit_l[(p_ * 8 + cib) * 16 + co];
                        lg[0] += d0; lg[16] += d1; lg[32] += d2; lg[48] += d3;
                    }
                }
            }
            __syncthreads();
        } else {
            if ((g & 1) == 0) {
#pragma unroll
                for (int rb = 0; rb < 4; ++rb)
#pragma unroll
                    for (int ct = 0; ct < 4; ++ct)
                        act_l[(rb * 2 + (g >> 1)) * 256 + (co_base + ct) * 16 + ao] =
                            actreg[rb][ct];
            }
            __syncthreads();
        }
    }

    // ---- coalesced output ----
    const int pixbase = ((b * 32 + h) * 32 + w0) * 256;
    for (int i = tid; i < 2048; i += 256)
        out[pixbase + i] = act_l[i];
}

extern "C" void kernel_launch(void* const* d_in, const int* in_sizes, int n_in,
                              void* d_out, int out_size, void* d_ws, size_t ws_size,
                              hipStream_t stream) {
    const float* x  = (const float*)d_in[0];
    const float* W  = (const float*)d_in[1];
    const float* bb = (const float*)d_in[2];
    float* out = (float*)d_out;
    unsigned short* Wt = (unsigned short*)d_ws;   // 409600 B needed

    hipLaunchKernelGGL(prep_weights, dim3(800), dim3(256), 0, stream, W, Wt);
    hipLaunchKernelGGL(caps_mfma, dim3(2048), dim3(256), 0, stream, x, Wt, bb, out);
}

// Round 3
// 207.100 us; speedup vs baseline: 4.3174x; 1.0012x over previous
//
#include <hip/hip_runtime.h>
#include <hip/hip_fp16.h>
#include <math.h>

// ConvCapsuleLayer v3: fp16 MFMA conv + fused routing, prep-converted inputs.
// x: [16,32,32,8,32] f32; W: [5,5,32,256] f32; b: [1,1,16,16] f32
// out: [16,32,32,16,16] f32
// d_ws: xb fp16 [16][32][36][256] (w-padded by 2 each side) + Wt fp16 [25][256][32]

typedef _Float16 f16;
typedef __attribute__((ext_vector_type(8))) _Float16 f16x8;
typedef __attribute__((ext_vector_type(4))) float f32x4;

#define STRIDE_CI 1944   // hw per ci slice: 5*12*32=1920 (+24; 1944/8=243 ≡ 3 mod 8)
#define XB_OFF 0
#define WT_OFF 9437184   // bytes: 16*32*36*256*2

__global__ void prep(const float* __restrict__ x, const float* __restrict__ W,
                     f16* __restrict__ xb, f16* __restrict__ Wt) {
    __shared__ f16 lw[32 * 260];
    const int tid = threadIdx.x;
    const int bid = blockIdx.x;
    if (bid < 4608) {
        // x -> xb [16][32][36][256] fp16, zero pad cols w' in {0,1,34,35}
        const int e4 = (bid * 256 + tid) * 4;
        const int c = e4 & 255;
        const int pix = e4 >> 8;
        const int wp = pix % 36;
        const int t = pix / 36;
        const int h = t & 31;
        const int b = t >> 5;
        const int w = wp - 2;
        f16 o[4] = {(f16)0.f, (f16)0.f, (f16)0.f, (f16)0.f};
        if ((unsigned)w < 32u) {
            const float4 v = *(const float4*)&x[(((b * 32 + h) * 32 + w) * 256) + c];
            o[0] = (f16)v.x; o[1] = (f16)v.y; o[2] = (f16)v.z; o[3] = (f16)v.w;
        }
        *(unsigned long long*)&xb[e4] = *(unsigned long long*)o;
    } else {
        // W [k5][ai][c] -> Wt [k5][c][ai] fp16 via LDS transpose
        const int k5 = bid - 4608;
        for (int rep = 0; rep < 32; ++rep) {
            const int idx = rep * 256 + tid;      // ai*256 + c
            const int ai = idx >> 8, cc = idx & 255;
            lw[ai * 260 + cc] = (f16)W[(k5 * 32 + ai) * 256 + cc];
        }
        __syncthreads();
        for (int rep = 0; rep < 32; ++rep) {
            const int o = rep * 256 + tid;        // c*32 + ai
            const int cc = o >> 5, ai = o & 31;
            Wt[k5 * 8192 + o] = lw[ai * 260 + cc];
        }
    }
}

__global__ __launch_bounds__(256, 3)
void caps_fp16(const f16* __restrict__ xb, const f16* __restrict__ Wt,
               const float* __restrict__ bptr, float* __restrict__ out) {
    __shared__ __align__(16) unsigned char smraw[8 * STRIDE_CI * 2];  // 31104 B
    f16* patch = (f16*)smraw;                       // conv phase
    float* logit_l = (float*)smraw;                 // [8][8][16] (routing phase)
    float* route_l = (float*)(smraw + 4096);        // [8][16][8]
    float* act_l   = (float*)(smraw + 8192);        // [8][256]
    __shared__ float bias_l[256];

    const int tid = threadIdx.x;
    const int lane = tid & 63;
    const int wv = tid >> 6;
    const int bid = blockIdx.x;
    const int w0 = (bid & 3) * 8;
    const int h = (bid >> 2) & 31;
    const int b = bid >> 7;

    bias_l[tid] = bptr[tid];

    // ---- stage patch: [ci][pos=dh*12+dw][ai] fp16, stride 1944/ci ----
    for (int e = tid; e < 1920; e += 256) {          // e = (pos*8 + ci)*4 + s
        const int pos = e >> 5;
        const int ci = (e >> 2) & 7;
        const int s = e & 3;
        const int dh = pos / 12, dw = pos - dh * 12;
        const int gh = h + dh - 2;
        f16x8 v = {};
        if ((unsigned)gh < 32u)
            v = *(const f16x8*)&xb[(((b * 32 + gh) * 36) + (w0 + dw)) * 256 + ci * 32 + s * 8];
        *(f16x8*)&patch[ci * STRIDE_CI + pos * 32 + s * 8] = v;
    }
    __syncthreads();

    // ---- conv: M=64 (p*8+ci), N=256 (co*16+ao), K=800 ----
    const int g = lane >> 4;
    const int q = lane & 15;
    const f16* aptr = patch + (lane & 7) * STRIDE_CI + ((lane >> 3) & 1) * 32 + g * 8;
    const f16* bbase = Wt + (wv * 64 + q) * 32 + g * 8;

    f32x4 acc[4][4];
#pragma unroll
    for (int rb = 0; rb < 4; ++rb)
#pragma unroll
        for (int ct = 0; ct < 4; ++ct) acc[rb][ct] = (f32x4)0.f;

    f16x8 Bc[4], Bn[4];
#pragma unroll
    for (int ct = 0; ct < 4; ++ct)
        Bc[ct] = *(const f16x8*)(bbase + ct * 512);

    int k5 = 0;
#pragma unroll
    for (int kh = 0; kh < 5; ++kh) {
#pragma unroll
        for (int kw = 0; kw < 5; ++kw) {
            if (k5 < 24) {
                const f16* bn = bbase + (k5 + 1) * 8192;
#pragma unroll
                for (int ct = 0; ct < 4; ++ct)
                    Bn[ct] = *(const f16x8*)(bn + ct * 512);
            }
            const f16* ap = aptr + (kh * 12 + kw) * 32;
            f16x8 A[4];
#pragma unroll
            for (int rb = 0; rb < 4; ++rb)
                A[rb] = *(const f16x8*)(ap + rb * 64);
#pragma unroll
            for (int rb = 0; rb < 4; ++rb)
#pragma unroll
                for (int ct = 0; ct < 4; ++ct)
                    acc[rb][ct] = __builtin_amdgcn_mfma_f32_16x16x32_f16(
                        A[rb], Bc[ct], acc[rb][ct], 0, 0, 0);
#pragma unroll
            for (int ct = 0; ct < 4; ++ct) Bc[ct] = Bn[ct];
            ++k5;
        }
    }
    // lane: acc[rb][ct][j] = votes[p=rb*2+(g>>1)][ci=(g&1)*4+j][co=wv*4+ct][ao=q]
    __syncthreads();   // patch dead; routing arrays (aliased) live from here

    // ---- routing ----
    const int co_base = wv * 4;
    const int ao = q;
    float actreg[4][4];

    for (int it = 0; it < 3; ++it) {
        if (it > 0) {
            // softmax over co: logit_l [p][ci][co] -> route_l [p][co][ci]
            for (int i = tid; i < 1024; i += 256) {
                const int p = i >> 7, ci = (i >> 4) & 7, co = i & 15;
                float lg = logit_l[i];
                float mx = lg;
#pragma unroll
                for (int m = 1; m < 16; m <<= 1) mx = fmaxf(mx, __shfl_xor(mx, m));
                float e = __expf(lg - mx);
                float s = e;
#pragma unroll
                for (int m = 1; m < 16; m <<= 1) s += __shfl_xor(s, m);
                route_l[(p * 16 + co) * 8 + ci] = e / s;
            }
            __syncthreads();
        }

        // preact + squash
#pragma unroll
        for (int rb = 0; rb < 4; ++rb) {
#pragma unroll
            for (int ct = 0; ct < 4; ++ct) {
                const int p_ = rb * 2 + (g >> 1);
                const int cib = (g & 1) * 4;
                const int co = co_base + ct;
                const f32x4 a = acc[rb][ct];
                float pr;
                if (it == 0) {
                    pr = 0.0625f * (a.x + a.y + a.z + a.w);   // uniform route
                } else {
                    const float4 r4 = *(const float4*)&route_l[(p_ * 16 + co) * 8 + cib];
                    pr = r4.x * a.x + r4.y * a.y + r4.z * a.z + r4.w * a.w;
                }
                pr += __shfl_xor(pr, 16);          // other ci-half (same p)
                pr += bias_l[co * 16 + ao];
                float sq = pr * pr;
#pragma unroll
                for (int m = 1; m < 16; m <<= 1) sq += __shfl_xor(sq, m);
                const float nrm = sqrtf(sq);
                actreg[rb][ct] = pr * nrm / (1.f + sq);
            }
        }

        if (it < 2) {
            // logits (it0: =, it1: +=)  d = sum_ao votes*act
#pragma unroll
            for (int rb = 0; rb < 4; ++rb) {
#pragma unroll
                for (int ct = 0; ct < 4; ++ct) {
                    const f32x4 a = acc[rb][ct];
                    const float av = actreg[rb][ct];
                    float d0 = a.x * av, d1 = a.y * av, d2 = a.z * av, d3 = a.w * av;
#pragma unroll
                    for (int m = 1; m < 16; m <<= 1) {
                        d0 += __shfl_xor(d0, m); d1 += __shfl_xor(d1, m);
                        d2 += __shfl_xor(d2, m); d3 += __shfl_xor(d3, m);
                    }
                    if (q == 0) {
                        const int p_ = rb * 2 + (g >> 1);
                        const int cib = (g & 1) * 4;
                        const int co = co_base + ct;
                        float* lg = &logit_l[(p_ * 8 + cib) * 16 + co];
                        if (it == 0) { lg[0] = d0; lg[16] = d1; lg[32] = d2; lg[48] = d3; }
                        else         { lg[0] += d0; lg[16] += d1; lg[32] += d2; lg[48] += d3; }
                    }
                }
            }
            __syncthreads();
        } else {
            if ((g & 1) == 0) {
#pragma unroll
                for (int rb = 0; rb < 4; ++rb)
#pragma unroll
                    for (int ct = 0; ct < 4; ++ct)
                        act_l[(rb * 2 + (g >> 1)) * 256 + (co_base + ct) * 16 + ao] =
                            actreg[rb][ct];
            }
            __syncthreads();
        }
    }

    // ---- coalesced output ----
    const int pixbase = ((b * 32 + h) * 32 + w0) * 256;
    for (int i = tid; i < 2048; i += 256)
        out[pixbase + i] = act_l[i];
}

extern "C" void kernel_launch(void* const* d_in, const int* in_sizes, int n_in,
                              void* d_out, int out_size, void* d_ws, size_t ws_size,
                              hipStream_t stream) {
    const float* x  = (const float*)d_in[0];
    const float* W  = (const float*)d_in[1];
    const float* bb = (const float*)d_in[2];
    float* out = (float*)d_out;
    f16* xb = (f16*)((char*)d_ws + XB_OFF);
    f16* Wt = (f16*)((char*)d_ws + WT_OFF);

    hipLaunchKernelGGL(prep, dim3(4608 + 25), dim3(256), 0, stream, x, W, xb, Wt);
    hipLaunchKernelGGL(caps_fp16, dim3(2048), dim3(256), 0, stream, xb, Wt, bb, out);
}

// Round 4
// 176.475 us; speedup vs baseline: 5.0666x; 1.1735x over previous
//
#include <hip/hip_runtime.h>
#include <hip/hip_fp16.h>
#include <math.h>

// ConvCapsuleLayer v4: 3-kernel split.
//   prep:      x -> xb fp16 (w-padded), W -> Wt fp16 transposed
//   caps_conv: MFMA fp16 conv -> votes fp16 (packed u32 pairs) in HBM
//   caps_route: votes -> LDS, 3 routing iterations with in-lane reductions
// Fallback (ws too small): v3 fused kernel.
// x: [16,32,32,8,32] f32; W: [5,5,32,256] f32; b: [1,1,16,16] f32
// out: [16,32,32,16,16] f32

typedef _Float16 f16;
typedef __attribute__((ext_vector_type(8))) _Float16 f16x8;
typedef __attribute__((ext_vector_type(4))) float f32x4;

#define STRIDE_CI 1944   // hw per ci slice: 5*12*32=1920 (+24)
#define XB_OFF 0
#define WT_OFF 9437184            // 16*32*36*256*2
#define VOTE_OFF 9846784          // WT_OFF + 25*256*32*2
#define WS_NEED 76955648ull       // VOTE_OFF + 2048*8192*4

static __device__ __forceinline__ float2 up16(unsigned int u) {
    union { unsigned int u; f16 h[2]; } c; c.u = u;
    return make_float2((float)c.h[0], (float)c.h[1]);
}

__global__ void prep(const float* __restrict__ x, const float* __restrict__ W,
                     f16* __restrict__ xb, f16* __restrict__ Wt) {
    __shared__ f16 lw[32 * 260];
    const int tid = threadIdx.x;
    const int bid = blockIdx.x;
    if (bid < 4608) {
        const int e4 = (bid * 256 + tid) * 4;
        const int c = e4 & 255;
        const int pix = e4 >> 8;
        const int wp = pix % 36;
        const int t = pix / 36;
        const int h = t & 31;
        const int b = t >> 5;
        const int w = wp - 2;
        f16 o[4] = {(f16)0.f, (f16)0.f, (f16)0.f, (f16)0.f};
        if ((unsigned)w < 32u) {
            const float4 v = *(const float4*)&x[(((b * 32 + h) * 32 + w) * 256) + c];
            o[0] = (f16)v.x; o[1] = (f16)v.y; o[2] = (f16)v.z; o[3] = (f16)v.w;
        }
        *(unsigned long long*)&xb[e4] = *(unsigned long long*)o;
    } else {
        const int k5 = bid - 4608;
        for (int rep = 0; rep < 32; ++rep) {
            const int idx = rep * 256 + tid;
            const int ai = idx >> 8, cc = idx & 255;
            lw[ai * 260 + cc] = (f16)W[(k5 * 32 + ai) * 256 + cc];
        }
        __syncthreads();
        for (int rep = 0; rep < 32; ++rep) {
            const int o = rep * 256 + tid;
            const int cc = o >> 5, ai = o & 31;
            Wt[k5 * 8192 + o] = lw[ai * 260 + cc];
        }
    }
}

// ---------------- conv -> votes ----------------
__global__ __launch_bounds__(256, 4)
void caps_conv(const f16* __restrict__ xb, const f16* __restrict__ Wt,
               unsigned int* __restrict__ votes) {
    __shared__ __align__(16) f16 patch[8 * STRIDE_CI];

    const int tid = threadIdx.x;
    const int lane = tid & 63;
    const int wv = tid >> 6;
    const int bid = blockIdx.x;
    const int w0 = (bid & 3) * 8;
    const int h = (bid >> 2) & 31;
    const int b = bid >> 7;

    for (int e = tid; e < 1920; e += 256) {
        const int pos = e >> 5;
        const int ci = (e >> 2) & 7;
        const int s = e & 3;
        const int dh = pos / 12, dw = pos - dh * 12;
        const int gh = h + dh - 2;
        f16x8 v = {};
        if ((unsigned)gh < 32u)
            v = *(const f16x8*)&xb[(((b * 32 + gh) * 36) + (w0 + dw)) * 256 + ci * 32 + s * 8];
        *(f16x8*)&patch[ci * STRIDE_CI + pos * 32 + s * 8] = v;
    }
    __syncthreads();

    const int g = lane >> 4;
    const int q = lane & 15;
    const f16* aptr = patch + (lane & 7) * STRIDE_CI + ((lane >> 3) & 1) * 32 + g * 8;
    const f16* bbase = Wt + (wv * 64 + q) * 32 + g * 8;

    f32x4 acc[4][4];
#pragma unroll
    for (int rb = 0; rb < 4; ++rb)
#pragma unroll
        for (int ct = 0; ct < 4; ++ct) acc[rb][ct] = (f32x4)0.f;

    f16x8 Bc[4], Bn[4];
#pragma unroll
    for (int ct = 0; ct < 4; ++ct)
        Bc[ct] = *(const f16x8*)(bbase + ct * 512);

    int k5 = 0;
#pragma unroll
    for (int kh = 0; kh < 5; ++kh) {
#pragma unroll
        for (int kw = 0; kw < 5; ++kw) {
            if (k5 < 24) {
                const f16* bn = bbase + (k5 + 1) * 8192;
#pragma unroll
                for (int ct = 0; ct < 4; ++ct)
                    Bn[ct] = *(const f16x8*)(bn + ct * 512);
            }
            const f16* ap = aptr + (kh * 12 + kw) * 32;
            f16x8 A[4];
#pragma unroll
            for (int rb = 0; rb < 4; ++rb)
                A[rb] = *(const f16x8*)(ap + rb * 64);
#pragma unroll
            for (int rb = 0; rb < 4; ++rb)
#pragma unroll
                for (int ct = 0; ct < 4; ++ct)
                    acc[rb][ct] = __builtin_amdgcn_mfma_f32_16x16x32_f16(
                        A[rb], Bc[ct], acc[rb][ct], 0, 0, 0);
#pragma unroll
            for (int ct = 0; ct < 4; ++ct) Bc[ct] = Bn[ct];
            ++k5;
        }
    }
    // acc[rb][ct][j] = votes[p=rb*2+(g>>1)][ci=(g&1)*4+j][co=wv*4+ct][ao=q]

    // pack fp16 pairs (ci-adjacent) and store lane-contiguous:
    // layout votes[blk][wv][rb][uh(2)][lane(64)][4] u32
#pragma unroll
    for (int rb = 0; rb < 4; ++rb) {
        unsigned int w[8];
#pragma unroll
        for (int ct = 0; ct < 4; ++ct) {
            union { f16 h[2]; unsigned int u; } c0, c1;
            c0.h[0] = (f16)acc[rb][ct].x; c0.h[1] = (f16)acc[rb][ct].y;
            c1.h[0] = (f16)acc[rb][ct].z; c1.h[1] = (f16)acc[rb][ct].w;
            w[ct * 2] = c0.u; w[ct * 2 + 1] = c1.u;
        }
        unsigned int* vp = votes + ((((size_t)bid * 4 + wv) * 4 + rb) * 2) * 256 + lane * 4;
        *(uint4*)vp = make_uint4(w[0], w[1], w[2], w[3]);
        *(uint4*)(vp + 256) = make_uint4(w[4], w[5], w[6], w[7]);
    }
}

// ---------------- routing ----------------
__global__ __launch_bounds__(256, 3)
void caps_route(const unsigned int* __restrict__ votes,
                const float* __restrict__ bptr, float* __restrict__ out) {
    __shared__ unsigned int vl[8 * 4 * 16 * 17];   // [p][cp][ao][co pad17]
    __shared__ float route_l[8 * 16 * 8];          // [p][co][ci]
    __shared__ float logit_l[8 * 8 * 16];          // [p][ci][co]
    __shared__ float act_l[8 * 16 * 17];           // [p][co][ao pad17]
    __shared__ float bias_l[256];

    const int tid = threadIdx.x;
    const int bid = blockIdx.x;
    bias_l[tid] = bptr[tid];

    // stage votes -> LDS scatter
    const uint4* vb = (const uint4*)(votes + (size_t)bid * 8192);
#pragma unroll
    for (int i = 0; i < 8; ++i) {
        const int f4 = i * 256 + tid;
        const uint4 v = vb[f4];
        const int lane = f4 & 63;
        const int uh = (f4 >> 6) & 1;
        const int rb = (f4 >> 7) & 3;
        const int wvv = (f4 >> 9) & 3;
        const int ao = lane & 15, g = lane >> 4;
        const int p = rb * 2 + (g >> 1);
        const int cpb = (g & 1) * 2;
        const unsigned int wc[4] = {v.x, v.y, v.z, v.w};
#pragma unroll
        for (int c = 0; c < 4; ++c) {
            const int ct = uh * 2 + (c >> 1);
            const int cp = cpb + (c & 1);
            const int co = wvv * 4 + ct;
            vl[((p * 4 + cp) * 16 + ao) * 17 + co] = wc[c];
        }
    }
    __syncthreads();

    const int p = tid >> 5;
    const int coh = (tid >> 4) & 1;
    const int ao = tid & 15;
    const int pa = tid >> 5, cpa = (tid >> 3) & 3, co8 = tid & 7;

    for (int it = 0; it < 3; ++it) {
        if (it > 0) {
            // softmax over co; write route transposed [p][co][ci]
            for (int i = tid; i < 1024; i += 256) {
                const int pp = i >> 7, ci = (i >> 4) & 7, co = i & 15;
                float lg = logit_l[i];
                float mx = lg;
#pragma unroll
                for (int m = 1; m < 16; m <<= 1) mx = fmaxf(mx, __shfl_xor(mx, m));
                float e = __expf(lg - mx);
                float s = e;
#pragma unroll
                for (int m = 1; m < 16; m <<= 1) s += __shfl_xor(s, m);
                route_l[(pp * 16 + co) * 8 + ci] = e / s;
            }
            __syncthreads();
        }

        // preact + squash: thread = (p, coh, ao), loop 8 co
        float actv[8];
#pragma unroll
        for (int c8 = 0; c8 < 8; ++c8) {
            const int co = coh * 8 + c8;
            float pr = bias_l[co * 16 + ao];
            if (it == 0) {
                float s = 0.f;
#pragma unroll
                for (int cp = 0; cp < 4; ++cp) {
                    const float2 vv = up16(vl[((p * 4 + cp) * 16 + ao) * 17 + co]);
                    s += vv.x + vv.y;
                }
                pr += 0.0625f * s;
            } else {
                const float4 r0 = *(const float4*)&route_l[(p * 16 + co) * 8];
                const float4 r1 = *(const float4*)&route_l[(p * 16 + co) * 8 + 4];
                const float2 v0 = up16(vl[((p * 4 + 0) * 16 + ao) * 17 + co]);
                const float2 v1 = up16(vl[((p * 4 + 1) * 16 + ao) * 17 + co]);
                const float2 v2 = up16(vl[((p * 4 + 2) * 16 + ao) * 17 + co]);
                const float2 v3 = up16(vl[((p * 4 + 3) * 16 + ao) * 17 + co]);
                pr += r0.x * v0.x + r0.y * v0.y + r0.z * v1.x + r0.w * v1.y
                    + r1.x * v2.x + r1.y * v2.y + r1.z * v3.x + r1.w * v3.y;
            }
            float sq = pr * pr;
#pragma unroll
            for (int m = 1; m < 16; m <<= 1) sq += __shfl_xor(sq, m);
            const float nrm = sqrtf(sq);
            actv[c8] = pr * nrm / (1.f + sq);
        }
#pragma unroll
        for (int c8 = 0; c8 < 8; ++c8)
            act_l[(p * 16 + coh * 8 + c8) * 17 + ao] = actv[c8];
        __syncthreads();

        if (it < 2) {
            // agreement: thread = (pa, cpa, co8); co in {co8, co8+8}, ci in {2cpa, 2cpa+1}
            float d00 = 0.f, d01 = 0.f, d10 = 0.f, d11 = 0.f;
            for (int a = 0; a < 16; ++a) {
                const unsigned int wA = vl[((pa * 4 + cpa) * 16 + a) * 17 + co8];
                const unsigned int wB = vl[((pa * 4 + cpa) * 16 + a) * 17 + co8 + 8];
                const float aA = act_l[(pa * 16 + co8) * 17 + a];
                const float aB = act_l[(pa * 16 + co8 + 8) * 17 + a];
                const float2 fA = up16(wA), fB = up16(wB);
                d00 += fA.x * aA; d01 += fA.y * aA;
                d10 += fB.x * aB; d11 += fB.y * aB;
            }
            float* l0 = &logit_l[(pa * 8 + cpa * 2) * 16 + co8];
            if (it == 0) { l0[0] = d00; l0[16] = d01; l0[8] = d10; l0[24] = d11; }
            else         { l0[0] += d00; l0[16] += d01; l0[8] += d10; l0[24] += d11; }
            __syncthreads();
        }
    }

    // output
    const int w0 = (bid & 3) * 8;
    const int h = (bid >> 2) & 31;
    const int b = bid >> 7;
    const size_t base = ((size_t)((b * 32 + h) * 32 + w0)) * 256;
    for (int i = tid; i < 2048; i += 256) {
        const int pp = i >> 8, co = (i >> 4) & 15, aoo = i & 15;
        out[base + i] = act_l[(pp * 16 + co) * 17 + aoo];
    }
}

// ---------------- fallback: v3 fused kernel ----------------
__global__ __launch_bounds__(256, 3)
void caps_fp16(const f16* __restrict__ xb, const f16* __restrict__ Wt,
               const float* __restrict__ bptr, float* __restrict__ out) {
    __shared__ __align__(16) unsigned char smraw[8 * STRIDE_CI * 2];
    f16* patch = (f16*)smraw;
    float* logit_l = (float*)smraw;
    float* route_l = (float*)(smraw + 4096);
    float* act_l   = (float*)(smraw + 8192);
    __shared__ float bias_l[256];

    const int tid = threadIdx.x;
    const int lane = tid & 63;
    const int wv = tid >> 6;
    const int bid = blockIdx.x;
    const int w0 = (bid & 3) * 8;
    const int h = (bid >> 2) & 31;
    const int b = bid >> 7;

    bias_l[tid] = bptr[tid];

    for (int e = tid; e < 1920; e += 256) {
        const int pos = e >> 5;
        const int ci = (e >> 2) & 7;
        const int s = e & 3;
        const int dh = pos / 12, dw = pos - dh * 12;
        const int gh = h + dh - 2;
        f16x8 v = {};
        if ((unsigned)gh < 32u)
            v = *(const f16x8*)&xb[(((b * 32 + gh) * 36) + (w0 + dw)) * 256 + ci * 32 + s * 8];
        *(f16x8*)&patch[ci * STRIDE_CI + pos * 32 + s * 8] = v;
    }
    __syncthreads();

    const int g = lane >> 4;
    const int q = lane & 15;
    const f16* aptr = patch + (lane & 7) * STRIDE_CI + ((lane >> 3) & 1) * 32 + g * 8;
    const f16* bbase = Wt + (wv * 64 + q) * 32 + g * 8;

    f32x4 acc[4][4];
#pragma unroll
    for (int rb = 0; rb < 4; ++rb)
#pragma unroll
        for (int ct = 0; ct < 4; ++ct) acc[rb][ct] = (f32x4)0.f;

    f16x8 Bc[4], Bn[4];
#pragma unroll
    for (int ct = 0; ct < 4; ++ct)
        Bc[ct] = *(const f16x8*)(bbase + ct * 512);

    int k5 = 0;
#pragma unroll
    for (int kh = 0; kh < 5; ++kh) {
#pragma unroll
        for (int kw = 0; kw < 5; ++kw) {
            if (k5 < 24) {
                const f16* bn = bbase + (k5 + 1) * 8192;
#pragma unroll
                for (int ct = 0; ct < 4; ++ct)
                    Bn[ct] = *(const f16x8*)(bn + ct * 512);
            }
            const f16* ap = aptr + (kh * 12 + kw) * 32;
            f16x8 A[4];
#pragma unroll
            for (int rb = 0; rb < 4; ++rb)
                A[rb] = *(const f16x8*)(ap + rb * 64);
#pragma unroll
            for (int rb = 0; rb < 4; ++rb)
#pragma unroll
                for (int ct = 0; ct < 4; ++ct)
                    acc[rb][ct] = __builtin_amdgcn_mfma_f32_16x16x32_f16(
                        A[rb], Bc[ct], acc[rb][ct], 0, 0, 0);
#pragma unroll
            for (int ct = 0; ct < 4; ++ct) Bc[ct] = Bn[ct];
            ++k5;
        }
    }
    __syncthreads();

    const int co_base = wv * 4;
    const int ao = q;
    float actreg[4][4];

    for (int it = 0; it < 3; ++it) {
        if (it > 0) {
            for (int i = tid; i < 1024; i += 256) {
                const int p = i >> 7, ci = (i >> 4) & 7, co = i & 15;
                float lg = logit_l[i];
                float mx = lg;
#pragma unroll
                for (int m = 1; m < 16; m <<= 1) mx = fmaxf(mx, __shfl_xor(mx, m));
                float e = __expf(lg - mx);
                float s = e;
#pragma unroll
                for (int m = 1; m < 16; m <<= 1) s += __shfl_xor(s, m);
                route_l[(p * 16 + co) * 8 + ci] = e / s;
            }
            __syncthreads();
        }

#pragma unroll
        for (int rb = 0; rb < 4; ++rb) {
#pragma unroll
            for (int ct = 0; ct < 4; ++ct) {
                const int p_ = rb * 2 + (g >> 1);
                const int cib = (g & 1) * 4;
                const int co = co_base + ct;
                const f32x4 a = acc[rb][ct];
                float pr;
                if (it == 0) {
                    pr = 0.0625f * (a.x + a.y + a.z + a.w);
                } else {
                    const float4 r4 = *(const float4*)&route_l[(p_ * 16 + co) * 8 + cib];
                    pr = r4.x * a.x + r4.y * a.y + r4.z * a.z + r4.w * a.w;
                }
                pr += __shfl_xor(pr, 16);
                pr += bias_l[co * 16 + ao];
                float sq = pr * pr;
#pragma unroll
                for (int m = 1; m < 16; m <<= 1) sq += __shfl_xor(sq, m);
                const float nrm = sqrtf(sq);
                actreg[rb][ct] = pr * nrm / (1.f + sq);
            }
        }

        if (it < 2) {
#pragma unroll
            for (int rb = 0; rb < 4; ++rb) {
#pragma unroll
                for (int ct = 0; ct < 4; ++ct) {
                    const f32x4 a = acc[rb][ct];
                    const float av = actreg[rb][ct];
                    float d0 = a.x * av, d1 = a.y * av, d2 = a.z * av, d3 = a.w * av;
#pragma unroll
                    for (int m = 1; m < 16; m <<= 1) {
                        d0 += __shfl_xor(d0, m); d1 += __shfl_xor(d1, m);
                        d2 += __shfl_xor(d2, m); d3 += __shfl_xor(d3, m);
                    }
                    if (q == 0) {
                        const int p_ = rb * 2 + (g >> 1);
                        const int cib = (g & 1) * 4;
                        const int co = co_base + ct;
                        float* lg = &logit_l[(p_ * 8 + cib) * 16 + co];
                        if (it == 0) { lg[0] = d0; lg[16] = d1; lg[32] = d2; lg[48] = d3; }
                        else         { lg[0] += d0; lg[16] += d1; lg[32] += d2; lg[48] += d3; }
                    }
                }
            }
            __syncthreads();
        } else {
            if ((g & 1) == 0) {
#pragma unroll
                for (int rb = 0; rb < 4; ++rb)
#pragma unroll
                    for (int ct = 0; ct < 4; ++ct)
                        act_l[(rb * 2 + (g >> 1)) * 256 + (co_base + ct) * 16 + ao] =
                            actreg[rb][ct];
            }
            __syncthreads();
        }
    }

    const int pixbase = ((b * 32 + h) * 32 + w0) * 256;
    for (int i = tid; i < 2048; i += 256)
        out[pixbase + i] = act_l[i];
}

extern "C" void kernel_launch(void* const* d_in, const int* in_sizes, int n_in,
                              void* d_out, int out_size, void* d_ws, size_t ws_size,
                              hipStream_t stream) {
    const float* x  = (const float*)d_in[0];
    const float* W  = (const float*)d_in[1];
    const float* bb = (const float*)d_in[2];
    float* out = (float*)d_out;
    f16* xb = (f16*)((char*)d_ws + XB_OFF);
    f16* Wt = (f16*)((char*)d_ws + WT_OFF);
    unsigned int* votes = (unsigned int*)((char*)d_ws + VOTE_OFF);

    hipLaunchKernelGGL(prep, dim3(4608 + 25), dim3(256), 0, stream, x, W, xb, Wt);
    if (ws_size >= WS_NEED) {
        hipLaunchKernelGGL(caps_conv, dim3(2048), dim3(256), 0, stream, xb, Wt, votes);
        hipLaunchKernelGGL(caps_route, dim3(2048), dim3(256), 0, stream, votes, bb, out);
    } else {
        hipLaunchKernelGGL(caps_fp16, dim3(2048), dim3(256), 0, stream, xb, Wt, bb, out);
    }
}

// Round 6
// 164.804 us; speedup vs baseline: 5.4254x; 1.0708x over previous
//
#include <hip/hip_runtime.h>
#include <hip/hip_fp16.h>
#include <math.h>

// ConvCapsuleLayer v5: fully fused single main kernel.
//   prep:    x -> xb fp16 (w-padded) ; W -> Wt fp16 transposed  (unchanged)
//   caps_v5: MFMA fp16 conv (depth-2 B prefetch) -> votes to LDS (aliasing
//            the dead input patch) -> v4-style routing core -> output.
// x: [16,32,32,8,32] f32; W: [5,5,32,256] f32; b: [1,1,16,16] f32
// out: [16,32,32,16,16] f32
// d_ws: xb fp16 [16][32][36][256] + Wt fp16 [25][256][32]  (~9.9 MB)

typedef _Float16 f16;
typedef __attribute__((ext_vector_type(8))) _Float16 f16x8;
typedef __attribute__((ext_vector_type(4))) float f32x4;

#define STRIDE_CI 1944   // hw per ci slice: 5*12*32=1920 (+24)
#define XB_OFF 0
#define WT_OFF 9437184   // bytes: 16*32*36*256*2

static __device__ __forceinline__ float2 up16(unsigned int u) {
    union { unsigned int u; f16 h[2]; } c; c.u = u;
    return make_float2((float)c.h[0], (float)c.h[1]);
}

__global__ void prep(const float* __restrict__ x, const float* __restrict__ W,
                     f16* __restrict__ xb, f16* __restrict__ Wt) {
    __shared__ f16 lw[32 * 260];
    const int tid = threadIdx.x;
    const int bid = blockIdx.x;
    if (bid < 4608) {
        const int e4 = (bid * 256 + tid) * 4;
        const int c = e4 & 255;
        const int pix = e4 >> 8;
        const int wp = pix % 36;
        const int t = pix / 36;
        const int h = t & 31;
        const int b = t >> 5;
        const int w = wp - 2;
        f16 o[4] = {(f16)0.f, (f16)0.f, (f16)0.f, (f16)0.f};
        if ((unsigned)w < 32u) {
            const float4 v = *(const float4*)&x[(((b * 32 + h) * 32 + w) * 256) + c];
            o[0] = (f16)v.x; o[1] = (f16)v.y; o[2] = (f16)v.z; o[3] = (f16)v.w;
        }
        *(unsigned long long*)&xb[e4] = *(unsigned long long*)o;
    } else {
        const int k5 = bid - 4608;
        for (int rep = 0; rep < 32; ++rep) {
            const int idx = rep * 256 + tid;
            const int ai = idx >> 8, cc = idx & 255;
            lw[ai * 260 + cc] = (f16)W[(k5 * 32 + ai) * 256 + cc];
        }
        __syncthreads();
        for (int rep = 0; rep < 32; ++rep) {
            const int o = rep * 256 + tid;
            const int cc = o >> 5, ai = o & 31;
            Wt[k5 * 8192 + o] = lw[ai * 260 + cc];
        }
    }
}

// ---------------- fused conv + routing ----------------
__global__ __launch_bounds__(256, 3)
void caps_v5(const f16* __restrict__ xb, const f16* __restrict__ Wt,
             const float* __restrict__ bptr, float* __restrict__ out) {
    // smraw: conv phase = patch fp16[8*1944] (31104 B)
    //        route phase = vl u32 [p=8][cp=4][ao=16][co pad17] (34816 B)
    __shared__ __align__(16) unsigned char smraw[34816];
    f16* patch = (f16*)smraw;
    unsigned int* vl = (unsigned int*)smraw;
    __shared__ float route_l[8 * 16 * 8];   // [p][co][ci]
    __shared__ float logit_l[8 * 8 * 16];   // [p][ci][co]
    __shared__ float act_l[8 * 16 * 17];    // [p][co][ao pad17]
    __shared__ float bias_l[256];

    const int tid = threadIdx.x;
    const int lane = tid & 63;
    const int wv = tid >> 6;
    const int bid = blockIdx.x;
    const int w0 = (bid & 3) * 8;
    const int h = (bid >> 2) & 31;
    const int b = bid >> 7;

    bias_l[tid] = bptr[tid];

    // ---- stage input patch ----
    for (int e = tid; e < 1920; e += 256) {
        const int pos = e >> 5;
        const int ci = (e >> 2) & 7;
        const int s = e & 3;
        const int dh = pos / 12, dw = pos - dh * 12;
        const int gh = h + dh - 2;
        f16x8 v = {};
        if ((unsigned)gh < 32u)
            v = *(const f16x8*)&xb[(((b * 32 + gh) * 36) + (w0 + dw)) * 256 + ci * 32 + s * 8];
        *(f16x8*)&patch[ci * STRIDE_CI + pos * 32 + s * 8] = v;
    }
    __syncthreads();

    // ---- conv: M=64 (p*8+ci), N=256 (co*16+ao), K=800 ----
    const int g = lane >> 4;
    const int q = lane & 15;
    const f16* aptr = patch + (lane & 7) * STRIDE_CI + ((lane >> 3) & 1) * 32 + g * 8;
    const f16* bbase = Wt + (wv * 64 + q) * 32 + g * 8;

    f32x4 acc[4][4];
#pragma unroll
    for (int rb = 0; rb < 4; ++rb)
#pragma unroll
        for (int ct = 0; ct < 4; ++ct) acc[rb][ct] = (f32x4)0.f;

    f16x8 Bc[4], Bn[4];
#pragma unroll
    for (int ct = 0; ct < 4; ++ct) {
        Bc[ct] = *(const f16x8*)(bbase + ct * 512);            // k5 = 0
        Bn[ct] = *(const f16x8*)(bbase + 8192 + ct * 512);     // k5 = 1
    }

    int k5 = 0;
#pragma unroll
    for (int kh = 0; kh < 5; ++kh) {
#pragma unroll
        for (int kw = 0; kw < 5; ++kw) {
            f16x8 Bf[4];
            if (k5 < 23) {                                     // prefetch k5+2
                const f16* bf = bbase + (k5 + 2) * 8192;
#pragma unroll
                for (int ct = 0; ct < 4; ++ct)
                    Bf[ct] = *(const f16x8*)(bf + ct * 512);
            }
            const f16* ap = aptr + (kh * 12 + kw) * 32;
            f16x8 A[4];
#pragma unroll
            for (int rb = 0; rb < 4; ++rb)
                A[rb] = *(const f16x8*)(ap + rb * 64);
#pragma unroll
            for (int rb = 0; rb < 4; ++rb)
#pragma unroll
                for (int ct = 0; ct < 4; ++ct)
                    acc[rb][ct] = __builtin_amdgcn_mfma_f32_16x16x32_f16(
                        A[rb], Bc[ct], acc[rb][ct], 0, 0, 0);
#pragma unroll
            for (int ct = 0; ct < 4; ++ct) { Bc[ct] = Bn[ct]; Bn[ct] = Bf[ct]; }
            ++k5;
        }
    }
    // acc[rb][ct][j] = votes[p=rb*2+(g>>1)][ci=(g&1)*4+j][co=wv*4+ct][ao=q]
    __syncthreads();   // patch dead — safe to overwrite with vl

    // ---- votes -> LDS (fp16 pairs, ci-adjacent) ----
#pragma unroll
    for (int rb = 0; rb < 4; ++rb) {
        const int p = rb * 2 + (g >> 1);
        const int cpb = (g & 1) * 2;
#pragma unroll
        for (int ct = 0; ct < 4; ++ct) {
            const int co = wv * 4 + ct;
            union { f16 h[2]; unsigned int u; } c0, c1;
            c0.h[0] = (f16)acc[rb][ct].x; c0.h[1] = (f16)acc[rb][ct].y;
            c1.h[0] = (f16)acc[rb][ct].z; c1.h[1] = (f16)acc[rb][ct].w;
            vl[((p * 4 + cpb) * 16 + q) * 17 + co] = c0.u;
            vl[((p * 4 + cpb + 1) * 16 + q) * 17 + co] = c1.u;
        }
    }
    __syncthreads();

    // ---- routing core (3 iterations) ----
    const int rp = tid >> 5;
    const int coh = (tid >> 4) & 1;
    const int ao = tid & 15;
    const int pa = tid >> 5, cpa = (tid >> 3) & 3, co8 = tid & 7;

    for (int it = 0; it < 3; ++it) {
        if (it > 0) {
            // softmax over co; route transposed [p][co][ci]
            for (int i = tid; i < 1024; i += 256) {
                const int pp = i >> 7, ci = (i >> 4) & 7, co = i & 15;
                float lg = logit_l[i];
                float mx = lg;
#pragma unroll
                for (int m = 1; m < 16; m <<= 1) mx = fmaxf(mx, __shfl_xor(mx, m));
                float e = __expf(lg - mx);
                float s = e;
#pragma unroll
                for (int m = 1; m < 16; m <<= 1) s += __shfl_xor(s, m);
                route_l[(pp * 16 + co) * 8 + ci] = e / s;
            }
            __syncthreads();
        }

        // preact + squash: thread = (rp, coh, ao), loop 8 co
        float actv[8];
#pragma unroll
        for (int c8 = 0; c8 < 8; ++c8) {
            const int co = coh * 8 + c8;
            float pr = bias_l[co * 16 + ao];
            if (it == 0) {
                float s = 0.f;
#pragma unroll
                for (int cp = 0; cp < 4; ++cp) {
                    const float2 vv = up16(vl[((rp * 4 + cp) * 16 + ao) * 17 + co]);
                    s += vv.x + vv.y;
                }
                pr += 0.0625f * s;
            } else {
                const float4 r0 = *(const float4*)&route_l[(rp * 16 + co) * 8];
                const float4 r1 = *(const float4*)&route_l[(rp * 16 + co) * 8 + 4];
                const float2 v0 = up16(vl[((rp * 4 + 0) * 16 + ao) * 17 + co]);
                const float2 v1 = up16(vl[((rp * 4 + 1) * 16 + ao) * 17 + co]);
                const float2 v2 = up16(vl[((rp * 4 + 2) * 16 + ao) * 17 + co]);
                const float2 v3 = up16(vl[((rp * 4 + 3) * 16 + ao) * 17 + co]);
                pr += r0.x * v0.x + r0.y * v0.y + r0.z * v1.x + r0.w * v1.y
                    + r1.x * v2.x + r1.y * v2.y + r1.z * v3.x + r1.w * v3.y;
            }
            float sq = pr * pr;
#pragma unroll
            for (int m = 1; m < 16; m <<= 1) sq += __shfl_xor(sq, m);
            const float nrm = sqrtf(sq);
            actv[c8] = pr * nrm / (1.f + sq);
        }
#pragma unroll
        for (int c8 = 0; c8 < 8; ++c8)
            act_l[(rp * 16 + coh * 8 + c8) * 17 + ao] = actv[c8];
        __syncthreads();

        if (it < 2) {
            // agreement: thread = (pa, cpa, co8); co in {co8, co8+8}, ci in {2cpa, 2cpa+1}
            float d00 = 0.f, d01 = 0.f, d10 = 0.f, d11 = 0.f;
            for (int a = 0; a < 16; ++a) {
                const unsigned int wA = vl[((pa * 4 + cpa) * 16 + a) * 17 + co8];
                const unsigned int wB = vl[((pa * 4 + cpa) * 16 + a) * 17 + co8 + 8];
                const float aA = act_l[(pa * 16 + co8) * 17 + a];
                const float aB = act_l[(pa * 16 + co8 + 8) * 17 + a];
                const float2 fA = up16(wA), fB = up16(wB);
                d00 += fA.x * aA; d01 += fA.y * aA;
                d10 += fB.x * aB; d11 += fB.y * aB;
            }
            float* l0 = &logit_l[(pa * 8 + cpa * 2) * 16 + co8];
            if (it == 0) { l0[0] = d00; l0[16] = d01; l0[8] = d10; l0[24] = d11; }
            else         { l0[0] += d00; l0[16] += d01; l0[8] += d10; l0[24] += d11; }
            __syncthreads();
        }
    }

    // ---- coalesced output ----
    const size_t base = ((size_t)((b * 32 + h) * 32 + w0)) * 256;
    for (int i = tid; i < 2048; i += 256) {
        const int pp = i >> 8, co = (i >> 4) & 15, aoo = i & 15;
        out[base + i] = act_l[(pp * 16 + co) * 17 + aoo];
    }
}

extern "C" void kernel_launch(void* const* d_in, const int* in_sizes, int n_in,
                              void* d_out, int out_size, void* d_ws, size_t ws_size,
                              hipStream_t stream) {
    const float* x  = (const float*)d_in[0];
    const float* W  = (const float*)d_in[1];
    const float* bb = (const float*)d_in[2];
    float* out = (float*)d_out;
    f16* xb = (f16*)((char*)d_ws + XB_OFF);
    f16* Wt = (f16*)((char*)d_ws + WT_OFF);

    hipLaunchKernelGGL(prep, dim3(4608 + 25), dim3(256), 0, stream, x, W, xb, Wt);
    hipLaunchKernelGGL(caps_v5, dim3(2048), dim3(256), 0, stream, xb, Wt, bb, out);
}

// Round 7
// 156.314 us; speedup vs baseline: 5.7201x; 1.0543x over previous
//
#include <hip/hip_runtime.h>
#include <hip/hip_fp16.h>
#include <math.h>

// ConvCapsuleLayer v6: fused conv+routing; fdot2 routing, conflict-swizzled LDS.
//   prep:    x -> xb fp16 (w-padded) ; W -> Wt fp16 transposed  (unchanged)
//   caps_v6: MFMA fp16 conv -> votes to LDS (pad-18 + p-parity offset) ->
//            routing with v_dot2_f32_f16 preact, fp16-pair route (broadcast),
//            XOR-ordered agreement loop, fast rcp/sqrt.
// x: [16,32,32,8,32] f32; W: [5,5,32,256] f32; b: [1,1,16,16] f32
// out: [16,32,32,16,16] f32

typedef _Float16 f16;
typedef __attribute__((ext_vector_type(2))) _Float16 f16x2;
typedef __attribute__((ext_vector_type(8))) _Float16 f16x8;
typedef __attribute__((ext_vector_type(4))) float f32x4;

#define STRIDE_CI 1944   // hw per ci slice: 5*12*32=1920 (+24)
#define XB_OFF 0
#define WT_OFF 9437184   // bytes: 16*32*36*256*2

// vote LDS index: [p][cp][ao] stride-18 dwords + parity offset; co in [0,16)
#define VIDX(p, cp, ao, co) ((((((p)*4 + (cp))*16 + (ao))*18) + (co)) + ((p) & 1))

static __device__ __forceinline__ float2 up16(unsigned int u) {
    union { unsigned int u; f16 h[2]; } c; c.u = u;
    return make_float2((float)c.h[0], (float)c.h[1]);
}

static __device__ __forceinline__ float fdot2u(unsigned int a, unsigned int b, float c) {
#if __has_builtin(__builtin_amdgcn_fdot2)
    union { unsigned int u; f16x2 h; } ua, ub;
    ua.u = a; ub.u = b;
    return __builtin_amdgcn_fdot2(ua.h, ub.h, c, false);
#else
    const float2 fa = up16(a), fb = up16(b);
    return c + fa.x * fb.x + fa.y * fb.y;
#endif
}

__global__ void prep(const float* __restrict__ x, const float* __restrict__ W,
                     f16* __restrict__ xb, f16* __restrict__ Wt) {
    __shared__ f16 lw[32 * 260];
    const int tid = threadIdx.x;
    const int bid = blockIdx.x;
    if (bid < 4608) {
        const int e4 = (bid * 256 + tid) * 4;
        const int c = e4 & 255;
        const int pix = e4 >> 8;
        const int wp = pix % 36;
        const int t = pix / 36;
        const int h = t & 31;
        const int b = t >> 5;
        const int w = wp - 2;
        f16 o[4] = {(f16)0.f, (f16)0.f, (f16)0.f, (f16)0.f};
        if ((unsigned)w < 32u) {
            const float4 v = *(const float4*)&x[(((b * 32 + h) * 32 + w) * 256) + c];
            o[0] = (f16)v.x; o[1] = (f16)v.y; o[2] = (f16)v.z; o[3] = (f16)v.w;
        }
        *(unsigned long long*)&xb[e4] = *(unsigned long long*)o;
    } else {
        const int k5 = bid - 4608;
        for (int rep = 0; rep < 32; ++rep) {
            const int idx = rep * 256 + tid;
            const int ai = idx >> 8, cc = idx & 255;
            lw[ai * 260 + cc] = (f16)W[(k5 * 32 + ai) * 256 + cc];
        }
        __syncthreads();
        for (int rep = 0; rep < 32; ++rep) {
            const int o = rep * 256 + tid;
            const int cc = o >> 5, ai = o & 31;
            Wt[k5 * 8192 + o] = lw[ai * 260 + cc];
        }
    }
}

// ---------------- fused conv + routing ----------------
__global__ __launch_bounds__(256, 3)
void caps_v6(const f16* __restrict__ xb, const f16* __restrict__ Wt,
             const float* __restrict__ bptr, float* __restrict__ out) {
    // conv phase: patch fp16[8*1944] = 31104 B
    // route phase: vl u32 [p8][cp4][ao16] stride-18 (+parity) = 36864 B
    __shared__ __align__(16) unsigned char smraw[36864];
    f16* patch = (f16*)smraw;
    unsigned int* vl = (unsigned int*)smraw;
    __shared__ __align__(16) unsigned int route_l[8 * 16 * 4]; // fp16 ci-pairs
    __shared__ float logit_l[8 * 8 * 17];   // [p][ci][co pad17]
    __shared__ float act_l[8 * 16 * 17];    // [p][co][ao pad17]
    __shared__ float bias_l[256];

    const int tid = threadIdx.x;
    const int lane = tid & 63;
    const int wv = tid >> 6;
    const int bid = blockIdx.x;
    const int w0 = (bid & 3) * 8;
    const int h = (bid >> 2) & 31;
    const int b = bid >> 7;

    bias_l[tid] = bptr[tid];

    // ---- stage input patch ----
    for (int e = tid; e < 1920; e += 256) {
        const int pos = e >> 5;
        const int ci = (e >> 2) & 7;
        const int s = e & 3;
        const int dh = pos / 12, dw = pos - dh * 12;
        const int gh = h + dh - 2;
        f16x8 v = {};
        if ((unsigned)gh < 32u)
            v = *(const f16x8*)&xb[(((b * 32 + gh) * 36) + (w0 + dw)) * 256 + ci * 32 + s * 8];
        *(f16x8*)&patch[ci * STRIDE_CI + pos * 32 + s * 8] = v;
    }
    __syncthreads();

    // ---- conv: M=64 (p*8+ci), N=256 (co*16+ao), K=800 ----
    const int g = lane >> 4;
    const int q = lane & 15;
    const f16* aptr = patch + (lane & 7) * STRIDE_CI + ((lane >> 3) & 1) * 32 + g * 8;
    const f16* bbase = Wt + (wv * 64 + q) * 32 + g * 8;

    f32x4 acc[4][4];
#pragma unroll
    for (int rb = 0; rb < 4; ++rb)
#pragma unroll
        for (int ct = 0; ct < 4; ++ct) acc[rb][ct] = (f32x4)0.f;

    f16x8 Bc[4], Bn[4];
#pragma unroll
    for (int ct = 0; ct < 4; ++ct) {
        Bc[ct] = *(const f16x8*)(bbase + ct * 512);            // k5 = 0
        Bn[ct] = *(const f16x8*)(bbase + 8192 + ct * 512);     // k5 = 1
    }

    int k5 = 0;
#pragma unroll
    for (int kh = 0; kh < 5; ++kh) {
#pragma unroll
        for (int kw = 0; kw < 5; ++kw) {
            f16x8 Bf[4];
            if (k5 < 23) {                                     // prefetch k5+2
                const f16* bf = bbase + (k5 + 2) * 8192;
#pragma unroll
                for (int ct = 0; ct < 4; ++ct)
                    Bf[ct] = *(const f16x8*)(bf + ct * 512);
            }
            const f16* ap = aptr + (kh * 12 + kw) * 32;
            f16x8 A[4];
#pragma unroll
            for (int rb = 0; rb < 4; ++rb)
                A[rb] = *(const f16x8*)(ap + rb * 64);
#pragma unroll
            for (int rb = 0; rb < 4; ++rb)
#pragma unroll
                for (int ct = 0; ct < 4; ++ct)
                    acc[rb][ct] = __builtin_amdgcn_mfma_f32_16x16x32_f16(
                        A[rb], Bc[ct], acc[rb][ct], 0, 0, 0);
#pragma unroll
            for (int ct = 0; ct < 4; ++ct) { Bc[ct] = Bn[ct]; Bn[ct] = Bf[ct]; }
            ++k5;
        }
    }
    // acc[rb][ct][j] = votes[p=rb*2+(g>>1)][ci=(g&1)*4+j][co=wv*4+ct][ao=q]
    __syncthreads();   // patch dead — safe to overwrite with vl

    // ---- votes -> LDS (fp16 pairs, ci-adjacent; cp = ci>>1) ----
#pragma unroll
    for (int rb = 0; rb < 4; ++rb) {
        const int p = rb * 2 + (g >> 1);
        const int cpb = (g & 1) * 2;
#pragma unroll
        for (int ct = 0; ct < 4; ++ct) {
            const int co = wv * 4 + ct;
            union { f16 h[2]; unsigned int u; } c0, c1;
            c0.h[0] = (f16)acc[rb][ct].x; c0.h[1] = (f16)acc[rb][ct].y;
            c1.h[0] = (f16)acc[rb][ct].z; c1.h[1] = (f16)acc[rb][ct].w;
            vl[VIDX(p, cpb, q, co)] = c0.u;
            vl[VIDX(p, cpb + 1, q, co)] = c1.u;
        }
    }
    __syncthreads();

    // ---- routing core (3 iterations) ----
    const int rp = tid >> 5;
    const int coh = (tid >> 4) & 1;
    const int ao = tid & 15;
    const int pa = tid >> 5, cpa = (tid >> 3) & 3, co8 = tid & 7;
    const int swz = (pa & 1) * 4 + cpa;          // agreement bank de-alias

    for (int it = 0; it < 3; ++it) {
        if (it > 0) {
            // softmax over co; route packed fp16 ci-pairs [p][co][cp]
            for (int i = tid; i < 1024; i += 256) {
                const int pp = i >> 7, ci = (i >> 4) & 7, co = i & 15;
                float lg = logit_l[(pp * 8 + ci) * 17 + co];
                float mx = lg;
#pragma unroll
                for (int m = 1; m < 16; m <<= 1) mx = fmaxf(mx, __shfl_xor(mx, m));
                float e = __expf(lg - mx);
                float s = e;
#pragma unroll
                for (int m = 1; m < 16; m <<= 1) s += __shfl_xor(s, m);
                const float r = e * __builtin_amdgcn_rcpf(s);
                const float rother = __shfl_xor(r, 16);   // partner ci^1
                if (((tid >> 4) & 1) == 0) {              // even-ci lanes pack
                    union { f16 h[2]; unsigned int u; } pk;
                    pk.h[0] = (f16)r; pk.h[1] = (f16)rother;
                    route_l[(pp * 16 + co) * 4 + (ci >> 1)] = pk.u;
                }
            }
            __syncthreads();
        }

        // preact + squash: thread = (rp, coh, ao), loop 8 co; fdot2 over ci-pairs
        float actv[8];
#pragma unroll
        for (int c8 = 0; c8 < 8; ++c8) {
            const int co = coh * 8 + c8;
            float pr = bias_l[co * 16 + ao];
            uint4 r4;
            if (it == 0) {
                r4.x = r4.y = r4.z = r4.w = 0x2C002C00u;  // (0.0625, 0.0625) fp16
            } else {
                r4 = *(const uint4*)&route_l[(rp * 16 + co) * 4];   // broadcast
            }
            pr = fdot2u(vl[VIDX(rp, 0, ao, co)], r4.x, pr);
            pr = fdot2u(vl[VIDX(rp, 1, ao, co)], r4.y, pr);
            pr = fdot2u(vl[VIDX(rp, 2, ao, co)], r4.z, pr);
            pr = fdot2u(vl[VIDX(rp, 3, ao, co)], r4.w, pr);
            float sq = pr * pr;
#pragma unroll
            for (int m = 1; m < 16; m <<= 1) sq += __shfl_xor(sq, m);
            const float nrm = __builtin_amdgcn_sqrtf(sq);
            actv[c8] = pr * nrm * __builtin_amdgcn_rcpf(1.f + sq);
        }
#pragma unroll
        for (int c8 = 0; c8 < 8; ++c8)
            act_l[(rp * 16 + coh * 8 + c8) * 17 + ao] = actv[c8];
        __syncthreads();

        if (it < 2) {
            // agreement: thread = (pa, cpa, co8); co in {co8, co8+8}, ci in {2cpa, 2cpa+1}
            float d00 = 0.f, d01 = 0.f, d10 = 0.f, d11 = 0.f;
#pragma unroll
            for (int a0 = 0; a0 < 16; ++a0) {
                const int a = a0 ^ swz;                       // bank de-alias order
                const unsigned int wA = vl[VIDX(pa, cpa, a, co8)];
                const unsigned int wB = vl[VIDX(pa, cpa, a, co8 + 8)];
                const float aA = act_l[(pa * 16 + co8) * 17 + a];
                const float aB = act_l[(pa * 16 + co8 + 8) * 17 + a];
                const float2 fA = up16(wA), fB = up16(wB);
                d00 += fA.x * aA; d01 += fA.y * aA;
                d10 += fB.x * aB; d11 += fB.y * aB;
            }
            float* l0 = &logit_l[(pa * 8 + cpa * 2) * 17 + co8];
            if (it == 0) { l0[0] = d00; l0[17] = d01; l0[8] = d10; l0[25] = d11; }
            else         { l0[0] += d00; l0[17] += d01; l0[8] += d10; l0[25] += d11; }
            __syncthreads();
        }
    }

    // ---- coalesced output ----
    const size_t base = ((size_t)((b * 32 + h) * 32 + w0)) * 256;
    for (int i = tid; i < 2048; i += 256) {
        const int pp = i >> 8, co = (i >> 4) & 15, aoo = i & 15;
        out[base + i] = act_l[(pp * 16 + co) * 17 + aoo];
    }
}

extern "C" void kernel_launch(void* const* d_in, const int* in_sizes, int n_in,
                              void* d_out, int out_size, void* d_ws, size_t ws_size,
                              hipStream_t stream) {
    const float* x  = (const float*)d_in[0];
    const float* W  = (const float*)d_in[1];
    const float* bb = (const float*)d_in[2];
    float* out = (float*)d_out;
    f16* xb = (f16*)((char*)d_ws + XB_OFF);
    f16* Wt = (f16*)((char*)d_ws + WT_OFF);

    hipLaunchKernelGGL(prep, dim3(4608 + 25), dim3(256), 0, stream, x, W, xb, Wt);
    hipLaunchKernelGGL(caps_v6, dim3(2048), dim3(256), 0, stream, xb, Wt, bb, out);
}

// Round 8
// 147.448 us; speedup vs baseline: 6.0640x; 1.0601x over previous
//
#include <hip/hip_runtime.h>
#include <hip/hip_fp16.h>
#include <math.h>

// ConvCapsuleLayer v7: fused conv+routing.
//   conv:    MFMA fp16, depth-1 A-prefetch + depth-2 B-prefetch.
//   routing: thread = (p, co, ao-half); preact/agreement in-lane over LDS votes,
//            act in registers, direct coalesced reg->global output.
// x: [16,32,32,8,32] f32; W: [5,5,32,256] f32; b: [1,1,16,16] f32
// out: [16,32,32,16,16] f32

typedef _Float16 f16;
typedef __attribute__((ext_vector_type(2))) _Float16 f16x2;
typedef __attribute__((ext_vector_type(8))) _Float16 f16x8;
typedef __attribute__((ext_vector_type(4))) float f32x4;

#define STRIDE_CI 1944   // hw per ci slice: 5*12*32=1920 (+24)
#define XB_OFF 0
#define WT_OFF 9437184   // bytes: 16*32*36*256*2

// vote LDS index: [p][cp][ao] stride-18 dwords + parity offset; co in [0,16)
#define VIDX(p, cp, ao, co) ((((((p)*4 + (cp))*16 + (ao))*18) + (co)) + ((p) & 1))

static __device__ __forceinline__ float2 up16(unsigned int u) {
    union { unsigned int u; f16 h[2]; } c; c.u = u;
    return make_float2((float)c.h[0], (float)c.h[1]);
}

static __device__ __forceinline__ float fdot2u(unsigned int a, unsigned int b, float c) {
#if __has_builtin(__builtin_amdgcn_fdot2)
    union { unsigned int u; f16x2 h; } ua, ub;
    ua.u = a; ub.u = b;
    return __builtin_amdgcn_fdot2(ua.h, ub.h, c, false);
#else
    const float2 fa = up16(a), fb = up16(b);
    return c + fa.x * fb.x + fa.y * fb.y;
#endif
}

__global__ void prep(const float* __restrict__ x, const float* __restrict__ W,
                     f16* __restrict__ xb, f16* __restrict__ Wt) {
    __shared__ f16 lw[32 * 260];
    const int tid = threadIdx.x;
    const int bid = blockIdx.x;
    if (bid < 4608) {
        const int e4 = (bid * 256 + tid) * 4;
        const int c = e4 & 255;
        const int pix = e4 >> 8;
        const int wp = pix % 36;
        const int t = pix / 36;
        const int h = t & 31;
        const int b = t >> 5;
        const int w = wp - 2;
        f16 o[4] = {(f16)0.f, (f16)0.f, (f16)0.f, (f16)0.f};
        if ((unsigned)w < 32u) {
            const float4 v = *(const float4*)&x[(((b * 32 + h) * 32 + w) * 256) + c];
            o[0] = (f16)v.x; o[1] = (f16)v.y; o[2] = (f16)v.z; o[3] = (f16)v.w;
        }
        *(unsigned long long*)&xb[e4] = *(unsigned long long*)o;
    } else {
        const int k5 = bid - 4608;
        for (int rep = 0; rep < 32; ++rep) {
            const int idx = rep * 256 + tid;
            const int ai = idx >> 8, cc = idx & 255;
            lw[ai * 260 + cc] = (f16)W[(k5 * 32 + ai) * 256 + cc];
        }
        __syncthreads();
        for (int rep = 0; rep < 32; ++rep) {
            const int o = rep * 256 + tid;
            const int cc = o >> 5, ai = o & 31;
            Wt[k5 * 8192 + o] = lw[ai * 260 + cc];
        }
    }
}

// ---------------- fused conv + routing ----------------
__global__ __launch_bounds__(256, 3)
void caps_v7(const f16* __restrict__ xb, const f16* __restrict__ Wt,
             const float* __restrict__ bptr, float* __restrict__ out) {
    // conv phase: patch fp16[8*1944] = 31104 B
    // route phase: vl u32 [p8][cp4][ao16] stride-18 (+parity) = 36864 B
    __shared__ __align__(16) unsigned char smraw[36864];
    f16* patch = (f16*)smraw;
    unsigned int* vl = (unsigned int*)smraw;
    __shared__ __align__(16) uint4 route_l[8 * 16];   // fp16 ci-pair quads per (p,co)
    __shared__ float logit_l[8 * 8 * 17];             // [p][ci][co pad17]
    __shared__ float bias_l[256];

    const int tid = threadIdx.x;
    const int lane = tid & 63;
    const int wv = tid >> 6;
    const int bid = blockIdx.x;
    const int w0 = (bid & 3) * 8;
    const int h = (bid >> 2) & 31;
    const int b = bid >> 7;

    bias_l[tid] = bptr[tid];

    // ---- stage input patch ----
    for (int e = tid; e < 1920; e += 256) {
        const int pos = e >> 5;
        const int ci = (e >> 2) & 7;
        const int s = e & 3;
        const int dh = pos / 12, dw = pos - dh * 12;
        const int gh = h + dh - 2;
        f16x8 v = {};
        if ((unsigned)gh < 32u)
            v = *(const f16x8*)&xb[(((b * 32 + gh) * 36) + (w0 + dw)) * 256 + ci * 32 + s * 8];
        *(f16x8*)&patch[ci * STRIDE_CI + pos * 32 + s * 8] = v;
    }
    __syncthreads();

    // ---- conv: M=64 (p*8+ci), N=256 (co*16+ao), K=800 ----
    const int g = lane >> 4;
    const int q = lane & 15;
    const f16* aptr = patch + (lane & 7) * STRIDE_CI + ((lane >> 3) & 1) * 32 + g * 8;
    const f16* bbase = Wt + (wv * 64 + q) * 32 + g * 8;

    f32x4 acc[4][4];
#pragma unroll
    for (int rb = 0; rb < 4; ++rb)
#pragma unroll
        for (int ct = 0; ct < 4; ++ct) acc[rb][ct] = (f32x4)0.f;

    f16x8 Bc[4], Bn[4];
    f16x8 Ac[4], An[4];
#pragma unroll
    for (int ct = 0; ct < 4; ++ct) {
        Bc[ct] = *(const f16x8*)(bbase + ct * 512);            // k5 = 0
        Bn[ct] = *(const f16x8*)(bbase + 8192 + ct * 512);     // k5 = 1
    }
#pragma unroll
    for (int rb = 0; rb < 4; ++rb)
        Ac[rb] = *(const f16x8*)(aptr + rb * 64);              // k5 = 0 (kh=kw=0)

    int k5 = 0;
#pragma unroll
    for (int kh = 0; kh < 5; ++kh) {
#pragma unroll
        for (int kw = 0; kw < 5; ++kw) {
            // prefetch A for k5+1 (constant-folded position; hides ds_read latency)
            if (k5 < 24) {
                const int n = k5 + 1;
                const f16* apn = aptr + ((n / 5) * 12 + (n % 5)) * 32;
#pragma unroll
                for (int rb = 0; rb < 4; ++rb)
                    An[rb] = *(const f16x8*)(apn + rb * 64);
            }
            // prefetch B for k5+2
            f16x8 Bf[4];
            if (k5 < 23) {
                const f16* bf = bbase + (k5 + 2) * 8192;
#pragma unroll
                for (int ct = 0; ct < 4; ++ct)
                    Bf[ct] = *(const f16x8*)(bf + ct * 512);
            }
#pragma unroll
            for (int rb = 0; rb < 4; ++rb)
#pragma unroll
                for (int ct = 0; ct < 4; ++ct)
                    acc[rb][ct] = __builtin_amdgcn_mfma_f32_16x16x32_f16(
                        Ac[rb], Bc[ct], acc[rb][ct], 0, 0, 0);
#pragma unroll
            for (int rb = 0; rb < 4; ++rb) Ac[rb] = An[rb];
#pragma unroll
            for (int ct = 0; ct < 4; ++ct) { Bc[ct] = Bn[ct]; Bn[ct] = Bf[ct]; }
            ++k5;
        }
    }
    // acc[rb][ct][j] = votes[p=rb*2+(g>>1)][ci=(g&1)*4+j][co=wv*4+ct][ao=q]
    __syncthreads();   // patch dead — safe to overwrite with vl

    // ---- votes -> LDS (fp16 pairs, ci-adjacent; cp = ci>>1) ----
#pragma unroll
    for (int rb = 0; rb < 4; ++rb) {
        const int p = rb * 2 + (g >> 1);
        const int cpb = (g & 1) * 2;
#pragma unroll
        for (int ct = 0; ct < 4; ++ct) {
            const int co = wv * 4 + ct;
            union { f16 h[2]; unsigned int u; } c0, c1;
            c0.h[0] = (f16)acc[rb][ct].x; c0.h[1] = (f16)acc[rb][ct].y;
            c1.h[0] = (f16)acc[rb][ct].z; c1.h[1] = (f16)acc[rb][ct].w;
            vl[VIDX(p, cpb, q, co)] = c0.u;
            vl[VIDX(p, cpb + 1, q, co)] = c1.u;
        }
    }
    __syncthreads();

    // ---- routing core: thread = (rp, rco, aoh); owns ao = aoh*8 .. +7 ----
    const int rp  = tid >> 5;
    const int rco = (tid >> 1) & 15;
    const int aoh = tid & 1;
    unsigned int* route_d = (unsigned int*)route_l;

    for (int it = 0; it < 3; ++it) {
        if (it > 0) {
            // softmax over co; pack route as fp16 ci-pairs into route_l[p*16+co]
            for (int i = tid; i < 1024; i += 256) {
                const int pp = i >> 7, ci = (i >> 4) & 7, co = i & 15;
                float lg = logit_l[(pp * 8 + ci) * 17 + co];
                float mx = lg;
#pragma unroll
                for (int m = 1; m < 16; m <<= 1) mx = fmaxf(mx, __shfl_xor(mx, m));
                float e = __expf(lg - mx);
                float s = e;
#pragma unroll
                for (int m = 1; m < 16; m <<= 1) s += __shfl_xor(s, m);
                const float r = e * __builtin_amdgcn_rcpf(s);
                const float rother = __shfl_xor(r, 16);   // partner ci^1
                if (((tid >> 4) & 1) == 0) {              // even-ci lanes pack
                    union { f16 h[2]; unsigned int u; } pk;
                    pk.h[0] = (f16)r; pk.h[1] = (f16)rother;
                    route_d[(pp * 16 + co) * 4 + (ci >> 1)] = pk.u;
                }
            }
            __syncthreads();
        }

        // preact + squash: 8 ao values in-lane
        uint4 r4;
        if (it == 0) {
            r4.x = r4.y = r4.z = r4.w = 0x2C002C00u;      // (0.0625, 0.0625) fp16
        } else {
            r4 = route_l[rp * 16 + rco];
        }
        float pr[8];
#pragma unroll
        for (int a8 = 0; a8 < 8; ++a8) {
            const int ao = aoh * 8 + a8;
            float v = bias_l[rco * 16 + ao];
            v = fdot2u(vl[VIDX(rp, 0, ao, rco)], r4.x, v);
            v = fdot2u(vl[VIDX(rp, 1, ao, rco)], r4.y, v);
            v = fdot2u(vl[VIDX(rp, 2, ao, rco)], r4.z, v);
            v = fdot2u(vl[VIDX(rp, 3, ao, rco)], r4.w, v);
            pr[a8] = v;
        }
        float sq = 0.f;
#pragma unroll
        for (int a8 = 0; a8 < 8; ++a8) sq += pr[a8] * pr[a8];
        sq += __shfl_xor(sq, 1);                           // partner ao-half
        const float scale = __builtin_amdgcn_sqrtf(sq) * __builtin_amdgcn_rcpf(1.f + sq);
        float actv[8];
#pragma unroll
        for (int a8 = 0; a8 < 8; ++a8) actv[a8] = pr[a8] * scale;

        if (it < 2) {
            // agreement: in-lane partials over own 8 ao, per ci; combine halves
            float part[8];
#pragma unroll
            for (int cp = 0; cp < 4; ++cp) {
                float e = 0.f, o = 0.f;
#pragma unroll
                for (int a8 = 0; a8 < 8; ++a8) {
                    const float2 f = up16(vl[VIDX(rp, cp, aoh * 8 + a8, rco)]);
                    e += f.x * actv[a8];
                    o += f.y * actv[a8];
                }
                part[cp * 2] = e; part[cp * 2 + 1] = o;
            }
#pragma unroll
            for (int ci = 0; ci < 8; ++ci) part[ci] += __shfl_xor(part[ci], 1);
            if (aoh == 0) {
#pragma unroll
                for (int ci = 0; ci < 8; ++ci) {
                    float* lp = &logit_l[(rp * 8 + ci) * 17 + rco];
                    if (it == 0) *lp = part[ci];
                    else         *lp += part[ci];
                }
            }
            __syncthreads();
        } else {
            // final: direct coalesced reg->global store
            const size_t base = ((size_t)((b * 32 + h) * 32 + w0)) * 256;
            float* dst = out + base + rp * 256 + rco * 16 + aoh * 8;
            *(float4*)dst       = make_float4(actv[0], actv[1], actv[2], actv[3]);
            *(float4*)(dst + 4) = make_float4(actv[4], actv[5], actv[6], actv[7]);
        }
    }
}

extern "C" void kernel_launch(void* const* d_in, const int* in_sizes, int n_in,
                              void* d_out, int out_size, void* d_ws, size_t ws_size,
                              hipStream_t stream) {
    const float* x  = (const float*)d_in[0];
    const float* W  = (const float*)d_in[1];
    const float* bb = (const float*)d_in[2];
    float* out = (float*)d_out;
    f16* xb = (f16*)((char*)d_ws + XB_OFF);
    f16* Wt = (f16*)((char*)d_ws + WT_OFF);

    hipLaunchKernelGGL(prep, dim3(4608 + 25), dim3(256), 0, stream, x, W, xb, Wt);
    hipLaunchKernelGGL(caps_v7, dim3(2048), dim3(256), 0, stream, xb, Wt, bb, out);
}